// Round 1
// baseline (703.794 us; speedup 1.0000x reference)
//
#include <hip/hip_runtime.h>
#include <hip/hip_bf16.h>

// Net_22625887715641: fused conv-feats + channel-normalize + 32x32 normalized
// cross-correlation (23x23 shifts, 362x362 templates).
//
// Outputs (concat, fp32): x1 [32][384][384] (4,718,592) then x2 [32][32][23][23] (541,696).
//
// Stage 2 is 1.42e11 FLOP -> bf16 MFMA. GEMM mapping:
//   out[o,c,dy,dx] = sum_{y,x} filt[o][y-dy_a][x] * prev[c][y+6*dy_b][x+dx],  dy = dy_a + 6*dy_b
//   M=(dy_a 0..5, o 0..31)=192, N=(cc 0..1, dy_b 0..3, dx 0..22)=184 (pad 192), K=(y outer, x 0..383)
// A read from global in packed [row][xb][o][8] bf16 layout (16B/lane coalesced).
// B rows staged in LDS as 8 shifted copies (stride 408 el = 816 B) so all
// ds_read_b128 are 16B aligned; shift s=dx&7 absorbed, base offset 8*(dx>>3).

typedef unsigned short ushort_t;
typedef __attribute__((ext_vector_type(8))) short bf16x8;   // 8 bf16 = 4 VGPRs
typedef __attribute__((ext_vector_type(4))) float f32x4;

#define EPSF 2.2204460492503131e-16f
#define X1_N (32*384*384)
#define X2_N (32*32*23*23)

// filtb: [372 rows][48 xb][32 o][8 xi] bf16; row = y+5 (y=0..361 data at rows 5..366), zeros elsewhere
#define FILTB_ELEMS (372*48*32*8)
// prevb: [32 c][392 rows][408 x] bf16; data rows 0..383, cols 0..383; zeros elsewhere
#define PREVB_ELEMS (32*392*408)
#define WS_BYTES ((size_t)(FILTB_ELEMS + PREVB_ELEMS)*2)

#define YMAX 367            // y-steps 0..366
#define NSTEP_CHUNK 12
#define NCHUNK 31           // 31*12 >= 367
#define INV_AREA (1.0f/131044.0f)

// ---------------------------------------------------------------------------
// Stage 1: conv (temp 3x11x11 + notemp 11x11), relu, /2 on temp, channel
// normalize. z=0: current x -> x1 (fp32 out) + filtb pack. z=1: prev -> prevb.
// Filters are wave-uniform -> scalar loads; pixels per-lane from L1/L2.
// ---------------------------------------------------------------------------
__global__ __launch_bounds__(256) void feat_kernel(
    const float* __restrict__ xcur, const float* __restrict__ xprev,
    const float* __restrict__ ft,   const float* __restrict__ fn,
    float* __restrict__ out_x1, ushort_t* __restrict__ filtb,
    ushort_t* __restrict__ prevb)
{
  const int tx = threadIdx.x & 15, ty = threadIdx.x >> 4;
  const int j = blockIdx.x * 16 + tx;   // 0..383
  const int i = blockIdx.y * 16 + ty;   // 0..383
  const int mode = blockIdx.z;          // 0 = current, 1 = prev
  const float* xin = mode ? xprev : xcur;

  float acc[32];
#pragma unroll
  for (int c = 0; c < 32; ++c) acc[c] = 0.f;

  for (int t = 0; t < 3; ++t) {
    for (int a = 0; a < 11; ++a) {
      const float* row = xin + (t * 394 + (i + a)) * 394 + j;
      const float* ftp = ft + (t * 11 + a) * 11;   // + ch*363 + b
      const float* fnp = fn + a * 11;              // + ch*121 + b
#pragma unroll
      for (int b = 0; b < 11; ++b) {
        float px = row[b];
#pragma unroll
        for (int ch = 0; ch < 16; ++ch)
          acc[ch] = fmaf(px, ftp[ch * 363 + b], acc[ch]);
        if (t == 2) {
#pragma unroll
          for (int ch = 0; ch < 16; ++ch)
            acc[16 + ch] = fmaf(px, fnp[ch * 121 + b], acc[16 + ch]);
        }
      }
    }
  }

  float s = EPSF;
#pragma unroll
  for (int c = 0; c < 32; ++c) {
    float v = fmaxf(acc[c], 0.f);
    if (c < 16) v *= 0.5f;               // temp channels: relu(conv)/2
    acc[c] = v;
    s += v;
  }
  const float inv = 1.f / s;

  if (mode == 0) {
    const bool inflt = (i >= 11) && (i <= 372) && (j >= 11) && (j <= 372);
    int fbase = 0;
    if (inflt) {
      const int rowr = i - 6;            // (i-11)+5
      const int xc = j - 11;
      fbase = ((rowr * 48 + (xc >> 3)) * 32) * 8 + (xc & 7);
    }
    __hip_bfloat16* fb = (__hip_bfloat16*)filtb;
#pragma unroll
    for (int c = 0; c < 32; ++c) {
      const float v = acc[c] * inv;
      out_x1[c * (384 * 384) + i * 384 + j] = v;
      if (inflt) fb[fbase + c * 8] = __float2bfloat16(v);
    }
  } else {
    __hip_bfloat16* pb = (__hip_bfloat16*)prevb;
#pragma unroll
    for (int c = 0; c < 32; ++c) {
      const float v = acc[c] * inv;
      pb[(c * 392 + i) * 408 + j] = __float2bfloat16(v);
    }
  }
}

// ---------------------------------------------------------------------------
// Stage 2: correlation via 16x16x32 bf16 MFMA.
// Grid: blockIdx.x = pair (16 c-pairs) + 16*chunk (31 y-chunks) = 496 WGs.
// Per WG: 4 waves; wave w owns Mt in {3w,3w+1,3w+2}; each wave all 12 Nt.
// acc: 3*12 f32x4 = 144 VGPRs. 2 blocks/CU (LDS 52.2KB, VGPR<=256).
// ---------------------------------------------------------------------------
__global__ __launch_bounds__(256, 2) void corr_kernel(
    const ushort_t* __restrict__ filtb, const ushort_t* __restrict__ prevb,
    float* __restrict__ x2)
{
  __shared__ ushort_t sB[2 * 4 * 8 * 408];   // [cc][dyb][s][408] = 26112 el = 52224 B

  const int tid = threadIdx.x;
  const int lane = tid & 63;
  const int w = tid >> 6;          // wave 0..3
  const int h = lane >> 4;         // quad 0..3
  const int nl = lane & 15;

  const int pair = blockIdx.x & 15;
  const int chunk = blockIdx.x >> 4;          // 0..30
  const int c0 = pair * 2;
  const int y0 = chunk * NSTEP_CHUNK;
  const int y1 = (y0 + NSTEP_CHUNK < YMAX) ? (y0 + NSTEP_CHUNK) : YMAX;

  // Per-lane B-fragment LDS byte offsets (Kt term added later). n -> (cc,dyb,dx).
  int boff[12];
#pragma unroll
  for (int nt = 0; nt < 12; ++nt) {
    int n = nt * 16 + nl;
    if (n >= 184) n = 183;                    // pad lanes: read valid data, never stored
    const int cc = n / 92;
    const int rem = n - 92 * cc;
    const int dyb = rem / 23;
    const int dx = rem - 23 * dyb;
    boff[nt] = ((((cc * 4 + dyb) * 8 + (dx & 7)) * 408) + h * 8 + (dx >> 3) * 8) * 2;
  }

  f32x4 acc[3][12];
  const f32x4 zero = {0.f, 0.f, 0.f, 0.f};
#pragma unroll
  for (int a = 0; a < 3; ++a)
#pragma unroll
    for (int b = 0; b < 12; ++b) acc[a][b] = zero;

  for (int y = y0; y < y1; ++y) {
    __syncthreads();
    {
      // Stage 8 rows (2cc x 4dyb) as 8 shifted copies each.
      const int s = tid & 7;
      const int q = (tid >> 3) & 3;
      const int rowi = tid >> 5;              // 0..7 = cc*4+dyb
      const int cc = rowi >> 2, dyb = rowi & 3;
      const ushort_t* src = prevb + ((size_t)((c0 + cc) * 392 + (y + 6 * dyb))) * 408;
      ushort_t* dst = sB + (rowi * 8 + s) * 408;
      for (int x = q; x < 408; x += 4)
        dst[x] = (x + s < 408) ? src[x + s] : (ushort_t)0;
    }
    __syncthreads();

    for (int Kt = 0; Kt < 12; ++Kt) {
      bf16x8 Af[3];
#pragma unroll
      for (int m3 = 0; m3 < 3; ++m3) {
        const int Mt = w * 3 + m3;
        const int row = y - (Mt >> 1) + 5;                 // y - dy_a + 5, in [0,371]
        const int o = ((Mt & 1) << 4) + nl;
        Af[m3] = *(const bf16x8*)(filtb + (((size_t)(row * 48 + Kt * 4 + h) * 32 + o) << 3));
      }
      bf16x8 Bf[12];
#pragma unroll
      for (int nt = 0; nt < 12; ++nt)
        Bf[nt] = *(const bf16x8*)((const char*)sB + boff[nt] + (Kt << 6));
#pragma unroll
      for (int m3 = 0; m3 < 3; ++m3)
#pragma unroll
        for (int nt = 0; nt < 12; ++nt)
          acc[m3][nt] = __builtin_amdgcn_mfma_f32_16x16x32_bf16(Af[m3], Bf[nt], acc[m3][nt], 0, 0, 0);
    }
  }

  // Epilogue: scale partials and atomically accumulate into x2[o][c][dy][dx].
#pragma unroll
  for (int nt = 0; nt < 12; ++nt) {
    const int n = nt * 16 + nl;
    if (n < 184) {
      const int cc = n / 92;
      const int rem = n - 92 * cc;
      const int dyb = rem / 23;
      const int dx = rem - 23 * dyb;
#pragma unroll
      for (int m3 = 0; m3 < 3; ++m3) {
        const int Mtb = (w * 3 + m3) * 16;
#pragma unroll
        for (int r = 0; r < 4; ++r) {
          const int m = Mtb + h * 4 + r;       // C/D layout: row=(lane>>4)*4+reg, col=lane&15
          const int o = m & 31;
          const int dy = (m >> 5) + 6 * dyb;   // dy_a + 6*dy_b
          if (dy <= 22)
            atomicAdd(&x2[((o * 32 + (c0 + cc)) * 23 + dy) * 23 + dx],
                      acc[m3][nt][r] * INV_AREA);
        }
      }
    }
  }
}

// ---------------------------------------------------------------------------
extern "C" void kernel_launch(void* const* d_in, const int* in_sizes, int n_in,
                              void* d_out, int out_size, void* d_ws, size_t ws_size,
                              hipStream_t stream)
{
  const float* x     = (const float*)d_in[0];   // [3][394][394]
  const float* xprev = (const float*)d_in[1];
  const float* ft    = (const float*)d_in[2];   // [16][3][11][11]
  const float* fn    = (const float*)d_in[3];   // [16][1][11][11]
  float* out = (float*)d_out;

  ushort_t* filtb = (ushort_t*)d_ws;
  ushort_t* prevb = filtb + FILTB_ELEMS;

  // Zero packed buffers (establishes zero padding) and the x2 accumulator region.
  hipMemsetAsync(d_ws, 0, WS_BYTES, stream);
  hipMemsetAsync(out + X1_N, 0, (size_t)X2_N * sizeof(float), stream);

  dim3 g1(24, 24, 2);
  feat_kernel<<<g1, 256, 0, stream>>>(x, xprev, ft, fn, out, filtb, prevb);

  corr_kernel<<<dim3(16 * NCHUNK), 256, 0, stream>>>(filtb, prevb, out + X1_N);
}

// Round 2
// 429.813 us; speedup vs baseline: 1.6374x; 1.6374x over previous
//
#include <hip/hip_runtime.h>
#include <hip/hip_bf16.h>

// Net_22625887715641: fused conv-feats + channel-normalize + 32x32 normalized
// cross-correlation (23x23 shifts, 362x362 templates).
//
// R2 changes vs R1 (528us corr, MfmaUtil 12.5%, latency-bound):
//  - XCD swizzle: grid 512, blockIdx = pair*32+chunk -> same-chunk pairs share
//    an XCD L2 (A working set 1.7MB < 4MB) instead of A from HBM.
//  - B staging: 2 phase-copies (even/odd ushort) built with funnel shifts and
//    written via aligned ds_write_b128 (was: 8 shifted copies, 2B scalar writes
//    -> 29.6k bank-conflict cycles per WG). B frags read as 4x aligned b32.
//  - Double-buffered sB: stage y+1 while computing y; 1 barrier per y-step.
//  - A fragments software-prefetched one Kt ahead (L2-latency hiding).

typedef unsigned short ushort_t;
typedef unsigned int uint_t;
typedef __attribute__((ext_vector_type(8))) short bf16x8;   // 8 bf16 = 4 VGPRs
typedef __attribute__((ext_vector_type(4))) float f32x4;
typedef __attribute__((ext_vector_type(4))) uint_t uint4_t;

#define EPSF 2.2204460492503131e-16f
#define X1_N (32*384*384)
#define X2_N (32*32*23*23)

// filtb: [372 rows][48 xb][32 o][8 xi] bf16; row = y+5 (y=0..361 data at rows 5..366)
#define FILTB_ELEMS (372*48*32*8)
// prevb: [32 c][392 rows][408 x] bf16; data rows 0..383, cols 0..383; zeros elsewhere
#define PREVB_ELEMS (32*392*408)
#define WS_BYTES ((size_t)(FILTB_ELEMS + PREVB_ELEMS)*2)

#define YMAX 367            // y-steps 0..366
#define NSTEP_CHUNK 12
#define NCHUNK 31           // 31*12 >= 367
#define NCHUNK_PAD 32       // grid rounded so blockIdx%8 == chunk%8 (XCD swizzle)
#define INV_AREA (1.0f/131044.0f)

// sB geometry (u32 words): [buf 2][rowi 8][copy 2][208]
#define SB_COPY_W 208       // 416 ushorts
#define SB_ROW_W  (2*SB_COPY_W)
#define SB_BUF_W  (8*SB_ROW_W)

// ---------------------------------------------------------------------------
// Stage 1: conv (temp 3x11x11 + notemp 11x11), relu, /2 on temp, channel
// normalize. z=0: current x -> x1 (fp32 out) + filtb pack. z=1: prev -> prevb.
// ---------------------------------------------------------------------------
__global__ __launch_bounds__(256) void feat_kernel(
    const float* __restrict__ xcur, const float* __restrict__ xprev,
    const float* __restrict__ ft,   const float* __restrict__ fn,
    float* __restrict__ out_x1, ushort_t* __restrict__ filtb,
    ushort_t* __restrict__ prevb)
{
  const int tx = threadIdx.x & 15, ty = threadIdx.x >> 4;
  const int j = blockIdx.x * 16 + tx;   // 0..383
  const int i = blockIdx.y * 16 + ty;   // 0..383
  const int mode = blockIdx.z;          // 0 = current, 1 = prev
  const float* xin = mode ? xprev : xcur;

  float acc[32];
#pragma unroll
  for (int c = 0; c < 32; ++c) acc[c] = 0.f;

  for (int t = 0; t < 3; ++t) {
    for (int a = 0; a < 11; ++a) {
      const float* row = xin + (t * 394 + (i + a)) * 394 + j;
      const float* ftp = ft + (t * 11 + a) * 11;   // + ch*363 + b
      const float* fnp = fn + a * 11;              // + ch*121 + b
#pragma unroll
      for (int b = 0; b < 11; ++b) {
        float px = row[b];
#pragma unroll
        for (int ch = 0; ch < 16; ++ch)
          acc[ch] = fmaf(px, ftp[ch * 363 + b], acc[ch]);
        if (t == 2) {
#pragma unroll
          for (int ch = 0; ch < 16; ++ch)
            acc[16 + ch] = fmaf(px, fnp[ch * 121 + b], acc[16 + ch]);
        }
      }
    }
  }

  float s = EPSF;
#pragma unroll
  for (int c = 0; c < 32; ++c) {
    float v = fmaxf(acc[c], 0.f);
    if (c < 16) v *= 0.5f;               // temp channels: relu(conv)/2
    acc[c] = v;
    s += v;
  }
  const float inv = 1.f / s;

  if (mode == 0) {
    const bool inflt = (i >= 11) && (i <= 372) && (j >= 11) && (j <= 372);
    int fbase = 0;
    if (inflt) {
      const int rowr = i - 6;            // (i-11)+5
      const int xc = j - 11;
      fbase = ((rowr * 48 + (xc >> 3)) * 32) * 8 + (xc & 7);
    }
    __hip_bfloat16* fb = (__hip_bfloat16*)filtb;
#pragma unroll
    for (int c = 0; c < 32; ++c) {
      const float v = acc[c] * inv;
      out_x1[c * (384 * 384) + i * 384 + j] = v;
      if (inflt) fb[fbase + c * 8] = __float2bfloat16(v);
    }
  } else {
    __hip_bfloat16* pb = (__hip_bfloat16*)prevb;
#pragma unroll
    for (int c = 0; c < 32; ++c) {
      const float v = acc[c] * inv;
      pb[(c * 392 + i) * 408 + j] = __float2bfloat16(v);
    }
  }
}

// ---------------------------------------------------------------------------
// Stage 2: correlation via 16x16x32 bf16 MFMA.
//   out[o,c,dy,dx] = sum_{y,x} filt[o][y-dy_a][x] * prev[c][y+6*dy_b][x+dx]
//   M=(dy_a,o)=192, N=(cc,dyb,dx)=184(pad 192), K=(y outer, x 0..383)
// Wave w: Mt {3w..3w+2}, all 12 Nt. acc 3*12 f32x4.
// ---------------------------------------------------------------------------
__global__ __launch_bounds__(256, 2) void corr_kernel(
    const ushort_t* __restrict__ filtb, const ushort_t* __restrict__ prevb,
    float* __restrict__ x2)
{
  __shared__ uint_t sB[2 * SB_BUF_W];   // 2*8*2*208 u32 = 26624 B

  const int tid = threadIdx.x;
  const int lane = tid & 63;
  const int w = tid >> 6;          // wave 0..3
  const int h = lane >> 4;         // quad 0..3
  const int nl = lane & 15;

  const int pair = blockIdx.x >> 5;            // 0..15
  const int chunk = blockIdx.x & 31;           // 0..31; %8 == XCD
  if (chunk >= NCHUNK) return;
  const int c0 = pair * 2;
  const int y0 = chunk * NSTEP_CHUNK;
  const int y1 = (y0 + NSTEP_CHUNK < YMAX) ? (y0 + NSTEP_CHUNK) : YMAX;

  // Per-lane B-fragment word offsets within a buffer (Kt*16 added later).
  int boffW[12];
#pragma unroll
  for (int nt = 0; nt < 12; ++nt) {
    int n = nt * 16 + nl;
    if (n >= 184) n = 183;                    // pad lanes: valid data, never stored
    const int cc = n / 92;
    const int rem = n - 92 * cc;
    const int dyb = rem / 23;
    const int dx = rem - 23 * dyb;
    const int rowi = cc * 4 + dyb;
    boffW[nt] = (rowi * 2 + (dx & 1)) * SB_COPY_W + (dx >> 1) + 4 * h;
  }

  // Staging role: row sr = cc*4+dyb, 32 lanes per row, chunk c covers words 4c..4c+4.
  const int sr = tid >> 5;                     // 0..7
  const int sl = tid & 31;

  f32x4 acc[3][12];
  const f32x4 zero = {0.f, 0.f, 0.f, 0.f};
#pragma unroll
  for (int a = 0; a < 3; ++a)
#pragma unroll
    for (int b = 0; b < 12; ++b) acc[a][b] = zero;

  const uint_t* prow_base =
      (const uint_t*)(prevb + ((size_t)((c0 + (sr >> 2)) * 392 + 6 * (sr & 3))) * 408);
  // row stride in words: 408*2B/4 = 204

  // ---- initial stage of y0 into buf 0 ----
  {
#pragma unroll
    for (int it = 0; it < 2; ++it) {
      const int c = sl + 32 * it;
      if (c < 51) {
        const uint_t* src = prow_base + (size_t)y0 * 204 + 4 * c;
        uint_t w0 = src[0], w1 = src[1], w2 = src[2], w3 = src[3], w4 = src[4];
        uint_t* dst = sB + sr * SB_ROW_W;
        ((uint4_t*)dst)[c] = uint4_t{w0, w1, w2, w3};
        const uint_t a0 = (w0 >> 16) | (w1 << 16);
        const uint_t a1 = (w1 >> 16) | (w2 << 16);
        const uint_t a2 = (w2 >> 16) | (w3 << 16);
        const uint_t a3 = (w3 >> 16) | (w4 << 16);
        ((uint4_t*)(dst + SB_COPY_W))[c] = uint4_t{a0, a1, a2, a3};
      }
    }
  }
  __syncthreads();

  int buf = 0;
  for (int y = y0; y < y1; ++y) {
    const bool hn = (y + 1 < y1);
    uint_t st[2][5];
    if (hn) {
      // issue next-y staging loads early; consumed after compute
#pragma unroll
      for (int it = 0; it < 2; ++it) {
        const int c = sl + 32 * it;
        if (c < 51) {
          const uint_t* src = prow_base + (size_t)(y + 1) * 204 + 4 * c;
#pragma unroll
          for (int q = 0; q < 5; ++q) st[it][q] = src[q];
        }
      }
    }

    // ---- compute y from sB[buf] ----
    const uint_t* sb = sB + buf * SB_BUF_W;
    bf16x8 Af[3], An[3];
#pragma unroll
    for (int m3 = 0; m3 < 3; ++m3) {
      const int Mt = w * 3 + m3;
      const int row = y - (Mt >> 1) + 5;
      const int o = ((Mt & 1) << 4) + nl;
      Af[m3] = *(const bf16x8*)(filtb + (((size_t)(row * 48 + h) * 32 + o) << 3));
    }
    for (int Kt = 0; Kt < 12; ++Kt) {
      const int Ktn = (Kt < 11) ? Kt + 1 : 11;
#pragma unroll
      for (int m3 = 0; m3 < 3; ++m3) {
        const int Mt = w * 3 + m3;
        const int row = y - (Mt >> 1) + 5;
        const int o = ((Mt & 1) << 4) + nl;
        An[m3] = *(const bf16x8*)(filtb + (((size_t)(row * 48 + Ktn * 4 + h) * 32 + o) << 3));
      }
#pragma unroll
      for (int nt = 0; nt < 12; ++nt) {
        const uint_t* p = sb + boffW[nt] + (Kt << 4);
        const uint4_t u = {p[0], p[1], p[2], p[3]};
        const bf16x8 Bf = __builtin_bit_cast(bf16x8, u);
#pragma unroll
        for (int m3 = 0; m3 < 3; ++m3)
          acc[m3][nt] = __builtin_amdgcn_mfma_f32_16x16x32_bf16(Af[m3], Bf, acc[m3][nt], 0, 0, 0);
      }
#pragma unroll
      for (int m3 = 0; m3 < 3; ++m3) Af[m3] = An[m3];
    }

    // ---- write staged y+1 into sB[buf^1] ----
    if (hn) {
      uint_t* dst = sB + (buf ^ 1) * SB_BUF_W + sr * SB_ROW_W;
#pragma unroll
      for (int it = 0; it < 2; ++it) {
        const int c = sl + 32 * it;
        if (c < 51) {
          const uint_t w0 = st[it][0], w1 = st[it][1], w2 = st[it][2],
                       w3 = st[it][3], w4 = st[it][4];
          ((uint4_t*)dst)[c] = uint4_t{w0, w1, w2, w3};
          const uint_t a0 = (w0 >> 16) | (w1 << 16);
          const uint_t a1 = (w1 >> 16) | (w2 << 16);
          const uint_t a2 = (w2 >> 16) | (w3 << 16);
          const uint_t a3 = (w3 >> 16) | (w4 << 16);
          ((uint4_t*)(dst + SB_COPY_W))[c] = uint4_t{a0, a1, a2, a3};
        }
      }
    }
    __syncthreads();
    buf ^= 1;
  }

  // Epilogue: scale partials and atomically accumulate into x2[o][c][dy][dx].
#pragma unroll
  for (int nt = 0; nt < 12; ++nt) {
    const int n = nt * 16 + nl;
    if (n < 184) {
      const int cc = n / 92;
      const int rem = n - 92 * cc;
      const int dyb = rem / 23;
      const int dx = rem - 23 * dyb;
#pragma unroll
      for (int m3 = 0; m3 < 3; ++m3) {
        const int Mtb = (w * 3 + m3) * 16;
#pragma unroll
        for (int r = 0; r < 4; ++r) {
          const int m = Mtb + h * 4 + r;       // C/D: row=(lane>>4)*4+reg, col=lane&15
          const int o = m & 31;
          const int dy = (m >> 5) + 6 * dyb;   // dy_a + 6*dy_b
          if (dy <= 22)
            atomicAdd(&x2[((o * 32 + (c0 + cc)) * 23 + dy) * 23 + dx],
                      acc[m3][nt][r] * INV_AREA);
        }
      }
    }
  }
}

// ---------------------------------------------------------------------------
extern "C" void kernel_launch(void* const* d_in, const int* in_sizes, int n_in,
                              void* d_out, int out_size, void* d_ws, size_t ws_size,
                              hipStream_t stream)
{
  const float* x     = (const float*)d_in[0];   // [3][394][394]
  const float* xprev = (const float*)d_in[1];
  const float* ft    = (const float*)d_in[2];   // [16][3][11][11]
  const float* fn    = (const float*)d_in[3];   // [16][1][11][11]
  float* out = (float*)d_out;

  ushort_t* filtb = (ushort_t*)d_ws;
  ushort_t* prevb = filtb + FILTB_ELEMS;

  // Zero packed buffers (establishes zero padding) and the x2 accumulator region.
  hipMemsetAsync(d_ws, 0, WS_BYTES, stream);
  hipMemsetAsync(out + X1_N, 0, (size_t)X2_N * sizeof(float), stream);

  dim3 g1(24, 24, 2);
  feat_kernel<<<g1, 256, 0, stream>>>(x, xprev, ft, fn, out, filtb, prevb);

  corr_kernel<<<dim3(16 * NCHUNK_PAD), 256, 0, stream>>>(filtb, prevb, out + X1_N);
}